// Round 4
// baseline (494.151 us; speedup 1.0000x reference)
//
#include <hip/hip_runtime.h>
#include <hip/hip_bf16.h>

typedef __attribute__((ext_vector_type(4))) float f32x4;
typedef __attribute__((ext_vector_type(8))) short short8;

__device__ __forceinline__ float bf2f(ushort u) {
    union { unsigned int u; float f; } x; x.u = ((unsigned int)u) << 16; return x.f;
}
__device__ __forceinline__ ushort f2bf(float f) {
    union { float f; unsigned int u; } x; x.f = f;
    unsigned int u = x.u;
    unsigned int r = (u + 0x7fffu + ((u >> 16) & 1u)) >> 16;  // RNE
    return (ushort)r;
}
__device__ __forceinline__ void gload16(const ushort* g, ushort* l) {
    __builtin_amdgcn_global_load_lds(
        (const __attribute__((address_space(1))) unsigned int*)g,
        (__attribute__((address_space(3))) unsigned int*)l, 16, 0, 0);
}

// ---------------------------------------------------------------------------
// k_wfold: grid 256 (o), 256 thr (i).  Every block recomputes the 4 softmax
// mask rows (cheap, no inter-kernel dep), then writes
// Wa[a][o][t*256+i] = bf16(m[a][t] * conv_w[o][i][t]).
// ---------------------------------------------------------------------------
__global__ __launch_bounds__(256) void k_wfold(
    const float* __restrict__ conv_w, const float* __restrict__ a_table,
    const float* __restrict__ a_W, const float* __restrict__ a_b,
    ushort* __restrict__ Wa)
{
    __shared__ float ao[4][9];
    __shared__ float m[4][9];
    const int o = blockIdx.x, tid = threadIdx.x;
    if (tid < 36) {
        const int a = tid / 9, t = tid % 9;
        float s = a_b[t];
        for (int c = 0; c < 32; c++) s += a_table[a * 32 + c] * a_W[t * 32 + c];
        ao[a][t] = s;
    }
    __syncthreads();
    if (tid < 4) {
        float mx = -1e30f;
        for (int t = 0; t < 9; t++) mx = fmaxf(mx, ao[tid][t]);
        float e[9], z = 0.f;
        for (int t = 0; t < 9; t++) { e[t] = expf(ao[tid][t] - mx); z += e[t]; }
        for (int t = 0; t < 9; t++) m[tid][t] = e[t] / z;
    }
    __syncthreads();
    float w9[9];
    #pragma unroll
    for (int t = 0; t < 9; t++) w9[t] = conv_w[(o * 256 + tid) * 9 + t];
    #pragma unroll
    for (int a = 0; a < 4; a++)
        #pragma unroll
        for (int t = 0; t < 9; t++)
            Wa[(size_t)((a << 8) + o) * 2304 + t * 256 + tid] = f2bf(m[a][t] * w9[t]);
}

// ---------------------------------------------------------------------------
// k_bucket: grid 24 x 256.  For each step j, bucket sample ids by action.
// cnt must be zeroed beforehand (hipMemsetAsync).
// ---------------------------------------------------------------------------
__global__ __launch_bounds__(256) void k_bucket(
    const int* __restrict__ actions, int* __restrict__ cnt, int* __restrict__ list)
{
    const int idx = blockIdx.x * 256 + threadIdx.x;   // 0..6143
    const int j = idx >> 11, b = idx & 2047;
    const int a = actions[b * 3 + j];
    const int pos = atomicAdd(&cnt[j * 4 + a], 1);
    list[((j * 4 + a) << 11) + pos] = b;
}

// ---------------------------------------------------------------------------
// k_lemb: grid B=2048, 256 thr (e).  c0[b][p][e] = bf16(sum_k map[idx][e]),
// idx==0 contributes 0.
// ---------------------------------------------------------------------------
__global__ __launch_bounds__(256) void k_lemb(
    const float* __restrict__ mapt, const int* __restrict__ lms,
    ushort* __restrict__ c0)
{
    const int b = blockIdx.x, e = threadIdx.x;
    for (int p = 0; p < 16; p++) {
        const int* lm = lms + (b * 16 + p) * 8;
        float s = 0.f;
        #pragma unroll
        for (int k = 0; k < 8; k++) {
            const int idx = lm[k];
            if (idx) s += mapt[idx * 256 + e];
        }
        c0[(size_t)(b * 16 + p) * 256 + e] = f2bf(s);
    }
}

// ---------------------------------------------------------------------------
// k_conv: one masked-conv step.  BM=256 (all o), BN=64 (4 same-action samples
// from bucket list), BK=64, 4 waves (2M x 2N), wave tile 128x32.
// A (= W_action) double-buffered in LDS via global_load_lds w=16 with XOR
// swizzle (pre-swizzled source, swizzled read).  B (= shifted cur) loaded
// global->reg directly (contiguous 16B per lane, L1/L2-resident).
// One barrier per K-step.
// ---------------------------------------------------------------------------
__global__ __launch_bounds__(256, 2) void k_conv(
    const ushort* __restrict__ cur, const ushort* __restrict__ Wa,
    const int* __restrict__ cnt, const int* __restrict__ list,
    const int j, ushort* __restrict__ outp)
{
    __shared__ __align__(16) ushort Alds[2][256 * 64];   // 2 x 32 KB
    const int tid = threadIdx.x;

    // ---- block -> (action bucket, sample slots), XCD-chunk swizzled ----
    const int c0n = cnt[j * 4 + 0], c1n = cnt[j * 4 + 1],
              c2n = cnt[j * 4 + 2], c3n = cnt[j * 4 + 3];
    const int t0 = (c0n + 3) >> 2;
    const int t1 = t0 + ((c1n + 3) >> 2);
    const int t2 = t1 + ((c2n + 3) >> 2);
    const int t3 = t2 + ((c3n + 3) >> 2);
    // bijective xcd swizzle for grid 516: q=64, r=4
    const int bid = blockIdx.x;
    const int xcd = bid & 7, sub = bid >> 3;
    const int wg = (xcd < 4 ? xcd * 65 : 260 + (xcd - 4) * 64) + sub;
    if (wg >= t3) return;                 // block-uniform exit, before barriers
    int a, off, ca;
    if      (wg < t0) { a = 0; off = 0;  ca = c0n; }
    else if (wg < t1) { a = 1; off = t0; ca = c1n; }
    else if (wg < t2) { a = 2; off = t1; ca = c2n; }
    else              { a = 3; off = t2; ca = c3n; }
    const int slot0 = (wg - off) * 4;
    const int* la = list + ((j * 4 + a) << 11);
    const ushort* wbase = Wa + (size_t)(a << 8) * 2304;

    // ---- wave coords ----
    const int wid = tid >> 6, lane = tid & 63;
    const int l15 = lane & 15, l4 = lane >> 4;
    const int wm = wid >> 1, wn = wid & 1;

    int sid[2]; bool vst[2];
    #pragma unroll
    for (int nf = 0; nf < 2; nf++) {
        const int sl = slot0 + wn * 2 + nf;
        vst[nf] = sl < ca;
        sid[nf] = vst[nf] ? la[sl] : 0;
    }

    // ---- staging: 8 x global_load_lds(16B) per thread covers 256x64 bf16 ----
    // LDS unit u = qq*256 + tid (16B units); row=u>>3, c_lds=u&7,
    // src chunk = c_lds ^ (row&7)  (inverse of the read-side XOR).
    const int srow = tid >> 3, sc = tid & 7;
    const int wubase = (tid & ~63) * 8;                  // wave-uniform, ushort units
    #define STAGE(buf, k0)                                                     \
        _Pragma("unroll")                                                      \
        for (int qq = 0; qq < 8; qq++) {                                       \
            const int row = qq * 32 + srow;                                    \
            const int cc = sc ^ (row & 7);                                     \
            gload16(wbase + (size_t)row * 2304 + (k0) + cc * 8,                \
                    &Alds[buf][qq * 2048 + wubase]);                           \
        }

    f32x4 acc[8][2];
    #pragma unroll
    for (int mf = 0; mf < 8; mf++) {
        acc[mf][0] = (f32x4){0.f, 0.f, 0.f, 0.f};
        acc[mf][1] = (f32x4){0.f, 0.f, 0.f, 0.f};
    }

    const short8 bzero = {0, 0, 0, 0, 0, 0, 0, 0};
    const int ph = l15 >> 2, pw = l15 & 3;
    STAGE(0, 0);

    int cb = 0;
    for (int ks = 0; ks < 36; ks++) {
        const int k0 = ks * 64;
        const int t = k0 >> 8, i0 = k0 & 255;
        const int hh = ph + t / 3 - 1, ww = pw + t % 3 - 1;
        const bool xv = (hh >= 0) & (hh < 4) & (ww >= 0) & (ww < 4);
        const int psrc = (hh << 2) + ww;

        __syncthreads();   // buf[cb] staged+visible; prior reads of buf[cb^1] done

        // B fragments: straight from global (L1/L2), contiguous 16B per lane
        short8 bfr[2][2];
        #pragma unroll
        for (int nf = 0; nf < 2; nf++)
            #pragma unroll
            for (int kf = 0; kf < 2; kf++) {
                const int i = i0 + kf * 32 + l4 * 8;
                const ushort* src = cur + ((size_t)sid[nf] * 16 + psrc) * 256 + i;
                bfr[nf][kf] = xv ? *(const short8*)src : bzero;
            }

        if (ks + 1 < 36) STAGE(cb ^ 1, k0 + 64);   // prefetch overlaps MFMA

        #pragma unroll
        for (int kf = 0; kf < 2; kf++) {
            #pragma unroll
            for (int mf = 0; mf < 8; mf++) {
                const int rr = wm * 128 + mf * 16 + l15;
                const int cc = (kf * 4 + l4) ^ (rr & 7);
                const short8 af = *(const short8*)&Alds[cb][rr * 64 + cc * 8];
                acc[mf][0] = __builtin_amdgcn_mfma_f32_16x16x32_bf16(
                    af, bfr[0][kf], acc[mf][0], 0, 0, 0);
                acc[mf][1] = __builtin_amdgcn_mfma_f32_16x16x32_bf16(
                    af, bfr[1][kf], acc[mf][1], 0, 0, 0);
            }
        }
        cb ^= 1;
    }

    // ---- epilogue: C frag col=l15 (=p), row=l4*4+r (=o) ----
    #pragma unroll
    for (int nf = 0; nf < 2; nf++) {
        if (!vst[nf]) continue;                      // wave-uniform branch
        const size_t rowb = ((size_t)sid[nf] * 16 + l15) * 256;
        #pragma unroll
        for (int mf = 0; mf < 8; mf++) {
            const int ob = wm * 128 + mf * 16 + l4 * 4;
            ushort o4[4];
            #pragma unroll
            for (int r = 0; r < 4; r++) o4[r] = f2bf(acc[mf][nf][r]);
            *(uint2*)&outp[rowb + ob] = *(const uint2*)o4;
        }
    }
    #undef STAGE
}

// ---------------------------------------------------------------------------
// k_final: grid B=2048.  Computes emb in-block (kills k_emb), then
// logits[p] = sum_s sum_e c_s[b][p][e]*emb[s][e], softmax chain, loss/acc.
// ---------------------------------------------------------------------------
__global__ __launch_bounds__(256) void k_final(
    const ushort* __restrict__ c0, const ushort* __restrict__ c1,
    const ushort* __restrict__ c2, const ushort* __restrict__ c3,
    const float* __restrict__ gold, const int* __restrict__ gs,
    const int* __restrict__ y, float* __restrict__ d_out)
{
    __shared__ float embl[4][256];
    __shared__ float red[256];
    __shared__ float lg[16];
    const int b = blockIdx.x, tid = threadIdx.x;
    {
        const int s = tid >> 6, e0 = (tid & 63) * 4;
        const int* g = gs + b * 64 + s * 16;
        float4 accv = make_float4(0.f, 0.f, 0.f, 0.f);
        #pragma unroll
        for (int l = 0; l < 16; l++) {
            const float4 v = *(const float4*)&gold[g[l] * 256 + e0];
            accv.x += v.x; accv.y += v.y; accv.z += v.z; accv.w += v.w;
        }
        *(float4*)&embl[s][e0] = accv;
    }
    __syncthreads();
    const int p = tid >> 4, g16 = tid & 15;
    const ushort* rows[4] = {
        c0 + (size_t)(b * 16 + p) * 256, c1 + (size_t)(b * 16 + p) * 256,
        c2 + (size_t)(b * 16 + p) * 256, c3 + (size_t)(b * 16 + p) * 256 };
    float acc = 0.f;
    #pragma unroll
    for (int s = 0; s < 4; s++) {
        const ushort* row = rows[s];
        const float* eb = embl[s];
        #pragma unroll 4
        for (int q = 0; q < 16; q++) {
            const int e = g16 + q * 16;
            acc += bf2f(row[e]) * eb[e];
        }
    }
    red[tid] = acc;
    __syncthreads();
    for (int st = 8; st >= 1; st >>= 1) {
        if (g16 < st) red[tid] += red[tid + st];
        __syncthreads();
    }
    if (g16 == 0) lg[p] = red[tid];
    __syncthreads();
    if (tid == 0) {
        float mx = -1e30f;
        for (int q = 0; q < 16; q++) mx = fmaxf(mx, lg[q]);
        float ex[16], z = 0.f;
        for (int q = 0; q < 16; q++) { ex[q] = expf(lg[q] - mx); z += ex[q]; }
        float prob[16];
        for (int q = 0; q < 16; q++) {
            prob[q] = ex[q] / z;
            d_out[2 + b * 16 + q] = prob[q];
        }
        int am = 0; float bv = prob[0];
        for (int q = 1; q < 16; q++) if (prob[q] > bv) { bv = prob[q]; am = q; }
        const int yt = y[b * 2] * 4 + y[b * 2 + 1];
        float z2 = 0.f;
        for (int q = 0; q < 16; q++) z2 += expf(prob[q]);
        const float logp = prob[yt] - logf(z2);
        atomicAdd(&d_out[0], -logp * (1.0f / 2048.0f));
        atomicAdd(&d_out[1], (am == yt) ? (1.0f / 2048.0f) : 0.0f);
    }
}

// ---------------------------------------------------------------------------
extern "C" void kernel_launch(void* const* d_in, const int* in_sizes, int n_in,
                              void* d_out, int out_size, void* d_ws, size_t ws_size,
                              hipStream_t stream) {
    const float* gold_table = (const float*)d_in[0];   // (11,256)
    const float* map_table  = (const float*)d_in[1];   // (128,256)
    const float* conv_w     = (const float*)d_in[2];   // (256,256,3,3)
    const float* a_table    = (const float*)d_in[3];   // (4,32)
    const float* a_W        = (const float*)d_in[4];   // (9,32)
    const float* a_b        = (const float*)d_in[5];   // (9,)
    const int*   gs         = (const int*)d_in[6];     // (2048,4,16)
    const int*   actions    = (const int*)d_in[7];     // (2048,3)
    const int*   lms        = (const int*)d_in[8];     // (2048,4,4,8)
    const int*   y          = (const int*)d_in[9];     // (2048,2)
    float* out = (float*)d_out;

    char* ws = (char*)d_ws;
    int*    cnt  = (int*)(ws + 0);                     // 48 B
    int*    list = (int*)(ws + 256);                   // 98,304 B
    ushort* Wa   = (ushort*)(ws + 131072);             // 4,718,592 B
    ushort* c0   = (ushort*)(ws + 4849664);            // 16,777,216 B each
    ushort* c1   = (ushort*)(ws + 21626880);
    ushort* c2   = (ushort*)(ws + 38404096);
    ushort* c3   = (ushort*)(ws + 55181312);           // end 71,958,528
    (void)in_sizes; (void)n_in; (void)out_size; (void)ws_size;

    hipMemsetAsync(cnt, 0, 48, stream);
    hipMemsetAsync(d_out, 0, 2 * sizeof(float), stream);
    k_wfold <<<256, 256, 0, stream>>>(conv_w, a_table, a_W, a_b, Wa);
    k_bucket<<<24, 256, 0, stream>>>(actions, cnt, list);
    k_lemb  <<<2048, 256, 0, stream>>>(map_table, lms, c0);
    k_conv  <<<516, 256, 0, stream>>>(c0, Wa, cnt, list, 0, c1);
    k_conv  <<<516, 256, 0, stream>>>(c1, Wa, cnt, list, 1, c2);
    k_conv  <<<516, 256, 0, stream>>>(c2, Wa, cnt, list, 2, c3);
    k_final <<<2048, 256, 0, stream>>>(c0, c1, c2, c3, gold_table, gs, y, out);
}

// Round 5
// 483.490 us; speedup vs baseline: 1.0220x; 1.0220x over previous
//
#include <hip/hip_runtime.h>
#include <hip/hip_bf16.h>

typedef __attribute__((ext_vector_type(4))) float f32x4;
typedef __attribute__((ext_vector_type(8))) short short8;

__device__ __forceinline__ float bf2f(ushort u) {
    union { unsigned int u; float f; } x; x.u = ((unsigned int)u) << 16; return x.f;
}
__device__ __forceinline__ ushort f2bf(float f) {
    union { float f; unsigned int u; } x; x.f = f;
    unsigned int u = x.u;
    unsigned int r = (u + 0x7fffu + ((u >> 16) & 1u)) >> 16;  // RNE
    return (ushort)r;
}
__device__ __forceinline__ void gload16(const ushort* g, ushort* l) {
    __builtin_amdgcn_global_load_lds(
        (const __attribute__((address_space(1))) unsigned int*)g,
        (__attribute__((address_space(3))) unsigned int*)l, 16, 0, 0);
}

// ---------------------------------------------------------------------------
// k_prep: grid 257.  Blocks 0..255 (= o): recompute masks locally, write
// Wa[a][o][t*256+i] = bf16(m[a][t]*conv_w[o][i][t]).  Block 256: zero cnt +
// loss/acc, then bucket sample ids by action for all 3 steps.
// ---------------------------------------------------------------------------
__global__ __launch_bounds__(256) void k_prep(
    const float* __restrict__ conv_w, const float* __restrict__ a_table,
    const float* __restrict__ a_W, const float* __restrict__ a_b,
    const int* __restrict__ actions, int* __restrict__ cnt,
    int* __restrict__ list, ushort* __restrict__ Wa,
    float* __restrict__ out_head)
{
    __shared__ float ao[4][9];
    __shared__ float m[4][9];
    const int bid = blockIdx.x, tid = threadIdx.x;
    if (bid < 256) {
        if (tid < 36) {
            const int a = tid / 9, t = tid % 9;
            float s = a_b[t];
            for (int c = 0; c < 32; c++) s += a_table[a * 32 + c] * a_W[t * 32 + c];
            ao[a][t] = s;
        }
        __syncthreads();
        if (tid < 4) {
            float mx = -1e30f;
            for (int t = 0; t < 9; t++) mx = fmaxf(mx, ao[tid][t]);
            float e[9], z = 0.f;
            for (int t = 0; t < 9; t++) { e[t] = expf(ao[tid][t] - mx); z += e[t]; }
            for (int t = 0; t < 9; t++) m[tid][t] = e[t] / z;
        }
        __syncthreads();
        const int o = bid;
        float w9[9];
        #pragma unroll
        for (int t = 0; t < 9; t++) w9[t] = conv_w[(o * 256 + tid) * 9 + t];
        #pragma unroll
        for (int a = 0; a < 4; a++)
            #pragma unroll
            for (int t = 0; t < 9; t++)
                Wa[(size_t)((a << 8) + o) * 2304 + t * 256 + tid] = f2bf(m[a][t] * w9[t]);
    } else {
        if (tid < 12) cnt[tid] = 0;
        if (tid == 0) { out_head[0] = 0.f; out_head[1] = 0.f; }
        __syncthreads();
        for (int it = 0; it < 24; it++) {
            const int idx = it * 256 + tid;          // 0..6143
            const int jj = idx >> 11, b = idx & 2047;
            const int av = actions[b * 3 + jj];
            const int pos = atomicAdd(&cnt[jj * 4 + av], 1);
            list[((jj * 4 + av) << 11) + pos] = b;
        }
    }
}

// ---------------------------------------------------------------------------
// k_lemb: grid B=2048, 256 thr (e).  c0[b][p][e] = bf16(sum_k map[idx][e]),
// idx==0 contributes 0.
// ---------------------------------------------------------------------------
__global__ __launch_bounds__(256) void k_lemb(
    const float* __restrict__ mapt, const int* __restrict__ lms,
    ushort* __restrict__ c0)
{
    const int b = blockIdx.x, e = threadIdx.x;
    for (int p = 0; p < 16; p++) {
        const int* lm = lms + (b * 16 + p) * 8;
        float s = 0.f;
        #pragma unroll
        for (int k = 0; k < 8; k++) {
            const int idx = lm[k];
            if (idx) s += mapt[idx * 256 + e];
        }
        c0[(size_t)(b * 16 + p) * 256 + e] = f2bf(s);
    }
}

// ---------------------------------------------------------------------------
// k_conv v2: BM=128 (om half), BN=64 (4 same-action samples), BK=64, 4 waves
// (2M x 2N), wave tile 64x32.  Grid 1032 = 2 om-halves x 516 groups, XCD-
// chunk swizzled (8 x 129).  LDS 2 x 16 KB double buffer -> 4 blocks/CU,
// 16 waves/CU.  A via global_load_lds w=16, XOR-swizzled (src pre-swizzle +
// read-side XOR).  B prefetched one K-step ahead into registers.
// ---------------------------------------------------------------------------
__global__ __launch_bounds__(256, 4) void k_conv(
    const ushort* __restrict__ cur, const ushort* __restrict__ Wa,
    const int* __restrict__ cnt, const int* __restrict__ list,
    const int j, ushort* __restrict__ outp)
{
    __shared__ __align__(16) ushort Alds[2][128 * 64];   // 2 x 16 KB
    const int tid = threadIdx.x;

    const int c0n = cnt[j * 4 + 0], c1n = cnt[j * 4 + 1],
              c2n = cnt[j * 4 + 2], c3n = cnt[j * 4 + 3];
    const int t0 = (c0n + 3) >> 2;
    const int t1 = t0 + ((c1n + 3) >> 2);
    const int t2 = t1 + ((c2n + 3) >> 2);
    const int t3 = t2 + ((c3n + 3) >> 2);
    const int bid = blockIdx.x;
    const int wg2 = (bid & 7) * 129 + (bid >> 3);        // bijective: 1032 = 8*129
    const int om  = wg2 >= 516 ? 1 : 0;
    const int g   = wg2 - om * 516;
    if (g >= t3) return;                  // block-uniform exit, before barriers
    int a, off, ca;
    if      (g < t0) { a = 0; off = 0;  ca = c0n; }
    else if (g < t1) { a = 1; off = t0; ca = c1n; }
    else if (g < t2) { a = 2; off = t1; ca = c2n; }
    else             { a = 3; off = t2; ca = c3n; }
    const int slot0 = (g - off) * 4;
    const int* la = list + ((j * 4 + a) << 11);
    const ushort* wbase = Wa + (size_t)(a << 8) * 2304 + (size_t)om * 128 * 2304;

    const int wid = tid >> 6, lane = tid & 63;
    const int l15 = lane & 15, l4 = lane >> 4;
    const int wm = wid >> 1, wn = wid & 1;

    int sid[2]; bool vst[2];
    #pragma unroll
    for (int nf = 0; nf < 2; nf++) {
        const int sl = slot0 + wn * 2 + nf;
        vst[nf] = sl < ca;
        sid[nf] = vst[nf] ? la[sl] : 0;
    }

    // staging: 4 x gload16 per thread covers 128x64 bf16 (16 KB).
    // unit u = qq*256+tid; row=u>>3, c_lds=u&7; src chunk = c_lds ^ (row&7).
    const int srow = tid >> 3, sc = tid & 7;
    #define STAGE(buf, k0)                                                     \
        _Pragma("unroll")                                                      \
        for (int qq = 0; qq < 4; qq++) {                                       \
            const int row = qq * 32 + srow;                                    \
            const int cc = sc ^ (row & 7);                                     \
            gload16(wbase + (size_t)row * 2304 + (k0) + cc * 8,                \
                    &Alds[buf][qq * 2048 + tid * 8]);                          \
        }

    f32x4 acc[4][2];
    #pragma unroll
    for (int mf = 0; mf < 4; mf++) {
        acc[mf][0] = (f32x4){0.f, 0.f, 0.f, 0.f};
        acc[mf][1] = (f32x4){0.f, 0.f, 0.f, 0.f};
    }

    const short8 bzero = {0, 0, 0, 0, 0, 0, 0, 0};
    const int ph = l15 >> 2, pw = l15 & 3;

    short8 bcur[2][2], bnxt[2][2];
    // B loader for K-step ks (ks=36 overrun reads valid memory, never used)
    #define LOADB(dst, ks)                                                     \
        {                                                                      \
            const int k0b = (ks) * 64;                                         \
            const int tb = k0b >> 8, i0b = k0b & 255;                          \
            const int hh = ph + tb / 3 - 1, ww = pw + tb % 3 - 1;              \
            const bool xv = (hh >= 0) & (hh < 4) & (ww >= 0) & (ww < 4);       \
            const int psrc = (hh << 2) + ww;                                   \
            _Pragma("unroll")                                                  \
            for (int nf = 0; nf < 2; nf++)                                     \
                _Pragma("unroll")                                              \
                for (int kf = 0; kf < 2; kf++) {                               \
                    const int i = i0b + kf * 32 + l4 * 8;                      \
                    const ushort* srcb =                                       \
                        cur + ((size_t)sid[nf] * 16 + psrc) * 256 + i;         \
                    dst[nf][kf] = xv ? *(const short8*)srcb : bzero;           \
                }                                                              \
        }

    LOADB(bcur, 0);
    STAGE(0, 0);

    int cb = 0;
    for (int ks = 0; ks < 36; ks++) {
        __syncthreads();   // buf[cb] staged+visible; prior reads of buf[cb^1] done
        if (ks + 1 < 36) STAGE(cb ^ 1, ks * 64 + 64);   // prefetch next A
        LOADB(bnxt, ks + 1);                            // prefetch next B (regs)

        #pragma unroll
        for (int kf = 0; kf < 2; kf++)
            #pragma unroll
            for (int mf = 0; mf < 4; mf++) {
                const int rr = wm * 64 + mf * 16 + l15;
                const int cc = (kf * 4 + l4) ^ (rr & 7);
                const short8 af = *(const short8*)&Alds[cb][rr * 64 + cc * 8];
                acc[mf][0] = __builtin_amdgcn_mfma_f32_16x16x32_bf16(
                    af, bcur[0][kf], acc[mf][0], 0, 0, 0);
                acc[mf][1] = __builtin_amdgcn_mfma_f32_16x16x32_bf16(
                    af, bcur[1][kf], acc[mf][1], 0, 0, 0);
            }
        #pragma unroll
        for (int nf = 0; nf < 2; nf++)
            #pragma unroll
            for (int kf = 0; kf < 2; kf++) bcur[nf][kf] = bnxt[nf][kf];
        cb ^= 1;
    }

    // epilogue: C frag col=l15 (=p), row=l4*4+r (=o)
    #pragma unroll
    for (int nf = 0; nf < 2; nf++) {
        if (!vst[nf]) continue;                      // wave-uniform branch
        const size_t rowb = ((size_t)sid[nf] * 16 + l15) * 256;
        #pragma unroll
        for (int mf = 0; mf < 4; mf++) {
            const int ob = om * 128 + wm * 64 + mf * 16 + l4 * 4;
            ushort o4[4];
            #pragma unroll
            for (int r = 0; r < 4; r++) o4[r] = f2bf(acc[mf][nf][r]);
            *(uint2*)&outp[rowb + ob] = *(const uint2*)o4;
        }
    }
    #undef STAGE
    #undef LOADB
}

// ---------------------------------------------------------------------------
// k_final: grid B=2048.  Computes emb in-block, then logits[p] =
// sum_s sum_e c_s[b][p][e]*emb[s][e], softmax chain, loss/acc atomics.
// ---------------------------------------------------------------------------
__global__ __launch_bounds__(256) void k_final(
    const ushort* __restrict__ c0, const ushort* __restrict__ c1,
    const ushort* __restrict__ c2, const ushort* __restrict__ c3,
    const float* __restrict__ gold, const int* __restrict__ gs,
    const int* __restrict__ y, float* __restrict__ d_out)
{
    __shared__ float embl[4][256];
    __shared__ float red[256];
    __shared__ float lg[16];
    const int b = blockIdx.x, tid = threadIdx.x;
    {
        const int s = tid >> 6, e0 = (tid & 63) * 4;
        const int* g = gs + b * 64 + s * 16;
        float4 accv = make_float4(0.f, 0.f, 0.f, 0.f);
        #pragma unroll
        for (int l = 0; l < 16; l++) {
            const float4 v = *(const float4*)&gold[g[l] * 256 + e0];
            accv.x += v.x; accv.y += v.y; accv.z += v.z; accv.w += v.w;
        }
        *(float4*)&embl[s][e0] = accv;
    }
    __syncthreads();
    const int p = tid >> 4, g16 = tid & 15;
    const ushort* rows[4] = {
        c0 + (size_t)(b * 16 + p) * 256, c1 + (size_t)(b * 16 + p) * 256,
        c2 + (size_t)(b * 16 + p) * 256, c3 + (size_t)(b * 16 + p) * 256 };
    float acc = 0.f;
    #pragma unroll
    for (int s = 0; s < 4; s++) {
        const ushort* row = rows[s];
        const float* eb = embl[s];
        #pragma unroll 4
        for (int q = 0; q < 16; q++) {
            const int e = g16 + q * 16;
            acc += bf2f(row[e]) * eb[e];
        }
    }
    red[tid] = acc;
    __syncthreads();
    for (int st = 8; st >= 1; st >>= 1) {
        if (g16 < st) red[tid] += red[tid + st];
        __syncthreads();
    }
    if (g16 == 0) lg[p] = red[tid];
    __syncthreads();
    if (tid == 0) {
        float mx = -1e30f;
        for (int q = 0; q < 16; q++) mx = fmaxf(mx, lg[q]);
        float ex[16], z = 0.f;
        for (int q = 0; q < 16; q++) { ex[q] = expf(lg[q] - mx); z += ex[q]; }
        float prob[16];
        for (int q = 0; q < 16; q++) {
            prob[q] = ex[q] / z;
            d_out[2 + b * 16 + q] = prob[q];
        }
        int am = 0; float bv = prob[0];
        for (int q = 1; q < 16; q++) if (prob[q] > bv) { bv = prob[q]; am = q; }
        const int yt = y[b * 2] * 4 + y[b * 2 + 1];
        float z2 = 0.f;
        for (int q = 0; q < 16; q++) z2 += expf(prob[q]);
        const float logp = prob[yt] - logf(z2);
        atomicAdd(&d_out[0], -logp * (1.0f / 2048.0f));
        atomicAdd(&d_out[1], (am == yt) ? (1.0f / 2048.0f) : 0.0f);
    }
}

// ---------------------------------------------------------------------------
extern "C" void kernel_launch(void* const* d_in, const int* in_sizes, int n_in,
                              void* d_out, int out_size, void* d_ws, size_t ws_size,
                              hipStream_t stream) {
    const float* gold_table = (const float*)d_in[0];   // (11,256)
    const float* map_table  = (const float*)d_in[1];   // (128,256)
    const float* conv_w     = (const float*)d_in[2];   // (256,256,3,3)
    const float* a_table    = (const float*)d_in[3];   // (4,32)
    const float* a_W        = (const float*)d_in[4];   // (9,32)
    const float* a_b        = (const float*)d_in[5];   // (9,)
    const int*   gs         = (const int*)d_in[6];     // (2048,4,16)
    const int*   actions    = (const int*)d_in[7];     // (2048,3)
    const int*   lms        = (const int*)d_in[8];     // (2048,4,4,8)
    const int*   y          = (const int*)d_in[9];     // (2048,2)
    float* out = (float*)d_out;

    char* ws = (char*)d_ws;
    int*    cnt  = (int*)(ws + 0);                     // 48 B
    int*    list = (int*)(ws + 256);                   // 98,304 B
    ushort* Wa   = (ushort*)(ws + 131072);             // 4,718,592 B
    ushort* c0   = (ushort*)(ws + 4849664);            // 16,777,216 B each
    ushort* c1   = (ushort*)(ws + 21626880);
    ushort* c2   = (ushort*)(ws + 38404096);
    ushort* c3   = (ushort*)(ws + 55181312);           // end 71,958,528
    (void)in_sizes; (void)n_in; (void)out_size; (void)ws_size;

    k_prep <<<257, 256, 0, stream>>>(conv_w, a_table, a_W, a_b, actions,
                                     cnt, list, Wa, out);
    k_lemb <<<2048, 256, 0, stream>>>(map_table, lms, c0);
    k_conv <<<1032, 256, 0, stream>>>(c0, Wa, cnt, list, 0, c1);
    k_conv <<<1032, 256, 0, stream>>>(c1, Wa, cnt, list, 1, c2);
    k_conv <<<1032, 256, 0, stream>>>(c2, Wa, cnt, list, 2, c3);
    k_final<<<2048, 256, 0, stream>>>(c0, c1, c2, c3, gold_table, gs, y, out);
}